// Round 5
// baseline (417.569 us; speedup 1.0000x reference)
//
#include <hip/hip_runtime.h>

// HetGNN fused kernel, round 19: transposed orientation -- the inter-layer
// transpose becomes free.
// R18 counters: LDS pipe ~65% busy (120 b128 weight reads + 320 ds_write_b16
// scatters/it at 8-way bank conflict, SQ_LDS_BANK_CONFLICT 5.37M), VALU 45%,
// MFMA 19%. The per-layer C->A scatter/gather transpose was simultaneously
// the VALU load, LDS-write load, conflicts, and the RAW chain.
// This round computes every layer OUTPUT-TRANSPOSED: H^T = W^T X^T with
// A-operand = weight (sW frags are layout-compatible: A and B lane layouts
// are identical), B-operand = activation. C-output col = graph-row m is
// exactly the lane dim the next B-operand needs; the k-dim (features) lives
// in registers. A fixed k-permutation pi -- slot(p,j) <-> feature
// 16*(j>>1) + 4p + 2f + (j&1), baked into the weight staging -- makes each
// lane's packed accumulator pairs DIRECTLY the next layer's B-frags: zero
// data movement between layers. All activation LDS, all 16-bit scatters,
// all bank conflicts and scatter->gather RAW round-trips are gone.
// Cross-lane glue that remains: mlp6 h-gather (8 ds_bpermute per neighbor
// tile, same-quarter pull), m1 k-swap (ds_swizzle lane^1), epilogue shuffles.
// w62 register-cached (32 VGPR). Single chain, ~115 VGPR demand under the
// 128 cap. LDS 100.3 KB (sW 96K + consts); no barriers after staging.

typedef unsigned short u16;
typedef unsigned int   u32;
typedef __attribute__((ext_vector_type(8))) short short8_t;
typedef __attribute__((ext_vector_type(2))) short short2v;
typedef __attribute__((ext_vector_type(4))) float floatx4;

// u16 offsets of each matrix's fragment block inside sW (fi*512 ordering).
// 96 frags: w51(16) w61(16) w71(16) w52(8) w53(8) w62(8) w63(8) w72(8) w73(8).
#define OFF_W51 0
#define OFF_W61 8192
#define OFF_W71 16384
#define OFF_W52 24576
#define OFF_W53 28672
#define OFF_W62 32768
#define OFF_W63 36864
#define OFF_W72 40960
#define OFF_W73 45056
#define WS_U16  49152

// f32 offsets inside the sConst LDS table.
// CB*: biases in NATURAL f_out order (read as float4 at 16t+4p).
// CWPO: wpost de-interleaved: [0..63] real, [64..127] imag (natural order).
// CWPA/CBPA/CBPE: 64 floats in pi-slot order (32f + 8p + j).
// CWPE: 2 x 64 in pi-slot order.
#define CB51 0
#define CB52 64
#define CB53 128
#define CB61 192
#define CB62 256
#define CB63 320
#define CB71 384
#define CB72 448
#define CB73 512
#define CWPO 576
#define CBPO 704
#define CWPA 768
#define CBPA 832
#define CWPE 896
#define CBPE 1024
#define CSZ  1088

struct Params {
  const float *ap, *ef;
  const float *wpa, *bpa, *wpe, *bpe;
  const float *w51, *b51, *w52, *b52, *w53, *b53;
  const float *w61, *b61, *w62, *b62, *w63, *b63;
  const float *w71, *b71, *w72, *b72, *w73, *b73;
  const float *wpost, *bpost;
  float *out;
  int gtot;
};

// Pack two f32 to bf16 pair: round-half-up via +0x8000, then one byte-perm.
// Low half = first arg (= even slot j).
__device__ __forceinline__ u32 pk2(float a, float b) {
  const u32 ua = __float_as_uint(a) + 0x8000u;
  const u32 ub = __float_as_uint(b) + 0x8000u;
  return __builtin_amdgcn_perm(ub, ua, 0x07060302u);  // {ub[31:16], ua[31:16]}
}
__device__ __forceinline__ float blo(u32 v) { return __uint_as_float(v << 16); }
__device__ __forceinline__ float bhi(u32 v) { return __uint_as_float(v & 0xffff0000u); }
// packed int16 max: exact bf16-max in our use because the final max-with-0
// (deferred relu) dominates any mis-ordered negative intermediate.
__device__ __forceinline__ u32 pkmax(u32 a, u32 b) {
  const short2v r = __builtin_elementwise_max(__builtin_bit_cast(short2v, a),
                                              __builtin_bit_cast(short2v, b));
  return __builtin_bit_cast(u32, r);
}
// lane ^= 1 exchange (BitMode swizzle, xor=1): rows (g,b,k) <-> (g,b,k^1).
__device__ __forceinline__ u32 swz1(u32 x) {
  return (u32)__builtin_amdgcn_ds_swizzle((int)x, 0x041F);
}

__device__ __forceinline__ floatx4 mfma16(short8_t a, short8_t b, floatx4 c) {
  return __builtin_amdgcn_mfma_f32_16x16x32_bf16(a, b, c, 0, 0, 0);
}
__device__ __forceinline__ short8_t ldW(const u16* B, int f, int l) {
  return *(const short8_t*)(B + f * 512 + l * 8);
}
__device__ __forceinline__ short8_t mkf(u32 a, u32 b, u32 c, u32 d) {
  uint4 v; v.x = a; v.y = b; v.z = c; v.w = d;
  return __builtin_bit_cast(short8_t, v);
}

__device__ __forceinline__ void init0(floatx4* acc) {
#pragma unroll
  for (int t = 0; t < 4; ++t) { acc[t][0] = 0.f; acc[t][1] = 0.f; acc[t][2] = 0.f; acc[t][3] = 0.f; }
}
// Bias init: acc[t][r] = bias[16t + 4p + r] (f_out-indexed, broadcast b128).
__device__ __forceinline__ void initB(floatx4* acc, const float* cb, int qp) {
#pragma unroll
  for (int t = 0; t < 4; ++t) {
    const float4 b = *(const float4*)(cb + 16 * t + 4 * qp);
    acc[t][0] = b.x; acc[t][1] = b.y; acc[t][2] = b.z; acc[t][3] = b.w;
  }
}

// 64->64 layer, weights from LDS: frags (t*TS+0, t*TS+1).
template<int TS>
__device__ __forceinline__ void layerT(floatx4* acc, const u16* W,
                                       short8_t b0, short8_t b1, int l) {
#pragma unroll
  for (int t = 0; t < 4; ++t) {
    acc[t] = mfma16(ldW(W, t * TS + 0, l), b0, acc[t]);
    acc[t] = mfma16(ldW(W, t * TS + 1, l), b1, acc[t]);
  }
}
// K=128 layer (concat input = 4 B-frags), weights = 16 frags (t*4+h).
__device__ __forceinline__ void layerT128(floatx4* acc, const u16* W,
                                          short8_t f0, short8_t f1,
                                          short8_t f2, short8_t f3, int l) {
#pragma unroll
  for (int t = 0; t < 4; ++t) {
    acc[t] = mfma16(ldW(W, t * 4 + 0, l), f0, acc[t]);
    acc[t] = mfma16(ldW(W, t * 4 + 1, l), f1, acc[t]);
    acc[t] = mfma16(ldW(W, t * 4 + 2, l), f2, acc[t]);
    acc[t] = mfma16(ldW(W, t * 4 + 3, l), f3, acc[t]);
  }
}
// 64->64 layer with register-cached weights.
__device__ __forceinline__ void layerB(floatx4* acc, const short8_t* Wc,
                                       short8_t b0, short8_t b1) {
#pragma unroll
  for (int t = 0; t < 4; ++t) {
    acc[t] = mfma16(Wc[2 * t + 0], b0, acc[t]);
    acc[t] = mfma16(Wc[2 * t + 1], b1, acc[t]);
  }
}

// relu + pack acc -> next-layer B-frags (pi order: frag0 = pk01[t], frag1 = pk23[t]).
__device__ __forceinline__ void packRf(short8_t& f0, short8_t& f1, const floatx4* a) {
  uint4 u0, u1;
  u0.x = pk2(fmaxf(a[0][0], 0.f), fmaxf(a[0][1], 0.f));
  u1.x = pk2(fmaxf(a[0][2], 0.f), fmaxf(a[0][3], 0.f));
  u0.y = pk2(fmaxf(a[1][0], 0.f), fmaxf(a[1][1], 0.f));
  u1.y = pk2(fmaxf(a[1][2], 0.f), fmaxf(a[1][3], 0.f));
  u0.z = pk2(fmaxf(a[2][0], 0.f), fmaxf(a[2][1], 0.f));
  u1.z = pk2(fmaxf(a[2][2], 0.f), fmaxf(a[2][3], 0.f));
  u0.w = pk2(fmaxf(a[3][0], 0.f), fmaxf(a[3][1], 0.f));
  u1.w = pk2(fmaxf(a[3][2], 0.f), fmaxf(a[3][3], 0.f));
  f0 = __builtin_bit_cast(short8_t, u0);
  f1 = __builtin_bit_cast(short8_t, u1);
}
// raw pack (relu deferred): d[2t] = pk(r0,r1), d[2t+1] = pk(r2,r3).
__device__ __forceinline__ void pack0(u32* d, const floatx4* a) {
#pragma unroll
  for (int t = 0; t < 4; ++t) {
    d[2 * t + 0] = pk2(a[t][0], a[t][1]);
    d[2 * t + 1] = pk2(a[t][2], a[t][3]);
  }
}

#define NBLK 256
#define NWAVE 8
#define PPW  4   // 256 blk * 8 waves * 4 pairs = 8192 pairs = 16384 graphs

__global__ __launch_bounds__(512, 2)
__attribute__((amdgpu_waves_per_eu(2, 2)))
void hetgnn_mfma(Params p) {
  __shared__ __align__(16) u16   sW[WS_U16];   // 96 KB weights (pi-k-order A-frags)
  __shared__ __align__(16) float sConst[CSZ];  // 4.25 KB

  const int tid  = threadIdx.x;
  const int wave = tid >> 6;
  const int l    = tid & 63;
  const int qp   = l >> 4;   // lane quarter
  const int c    = l & 15;   // graph-row column: (g = c>>3, b = (c>>1)&3, k = c&1)

  // ---- stage + swizzle weights: f32 global -> bf16 A-frags in pi-k-order.
  //      A-frag (t,h): value(lane l, j) = W[kidx, 16t + (l&15)]
  //      K=64 mats:  kidx = 16*(j>>1) + 4*(l>>4) + 2*h + (j&1)
  //      K=128 mats: kidx = 64*(h>>1) + 16*(j>>1) + 4*(l>>4) + 2*(h&1) + (j&1)
  {
    for (int fi = wave; fi < 96; fi += NWAVE) {   // wave-uniform fi, 12/wave
      int t, h, mi;
      if (fi < 48) { mi = fi >> 4; const int loc = fi & 15; t = loc >> 2; h = loc & 3; }
      else { const int j2 = fi - 48; mi = 3 + (j2 >> 3); const int loc = j2 & 7; t = loc >> 1; h = loc & 1; }
      const float* W =
          (mi == 0) ? p.w51 : (mi == 1) ? p.w61 : (mi == 2) ? p.w71 :
          (mi == 3) ? p.w52 : (mi == 4) ? p.w53 : (mi == 5) ? p.w62 :
          (mi == 6) ? p.w63 : (mi == 7) ? p.w72 : p.w73;
      const int nn = 16 * t + c;
      float w[8];
#pragma unroll
      for (int jj = 0; jj < 8; ++jj) {
        const int kidx = (fi < 48)
            ? 64 * (h >> 1) + 16 * (jj >> 1) + 4 * qp + 2 * (h & 1) + (jj & 1)
            : 16 * (jj >> 1) + 4 * qp + 2 * h + (jj & 1);
        w[jj] = W[kidx * 64 + nn];
      }
      uint4 o;
      o.x = pk2(w[0], w[1]); o.y = pk2(w[2], w[3]);
      o.z = pk2(w[4], w[5]); o.w = pk2(w[6], w[7]);
      *(uint4*)(sW + fi * 512 + l * 8) = o;
    }
  }
  if (tid < 64) {
    // biases: natural f_out order
    sConst[CB51 + tid] = p.b51[tid];
    sConst[CB52 + tid] = p.b52[tid];
    sConst[CB53 + tid] = p.b53[tid];
    sConst[CB61 + tid] = p.b61[tid];
    sConst[CB62 + tid] = p.b62[tid];
    sConst[CB63 + tid] = p.b63[tid];
    sConst[CB71 + tid] = p.b71[tid];
    sConst[CB72 + tid] = p.b72[tid];
    sConst[CB73 + tid] = p.b73[tid];
    // wpost de-interleaved (natural order)
    sConst[CWPO + tid]      = p.wpost[2 * tid];
    sConst[CWPO + 64 + tid] = p.wpost[2 * tid + 1];
    // pre-layer weights/biases in pi-slot order: slot tid = 32f + 8p + j
    {
      const int f = tid >> 5, pp = (tid >> 3) & 3, jj = tid & 7;
      const int feat = 16 * (jj >> 1) + 4 * pp + 2 * f + (jj & 1);
      sConst[CWPA + tid] = p.wpa[feat];
      sConst[CBPA + tid] = p.bpa[feat];
      sConst[CBPE + tid] = p.bpe[feat];
    }
  }
  if (tid < 128) {
    const int s = tid & 63;
    const int f = s >> 5, pp = (s >> 3) & 3, jj = s & 7;
    const int feat = 16 * (jj >> 1) + 4 * pp + 2 * f + (jj & 1);
    sConst[CWPE + tid] = p.wpe[(tid >> 6) * 64 + feat];
  }
  if (tid < 2) sConst[CBPO + tid] = p.bpost[tid];
  __syncthreads();

  // ---- w62 (used 3x per it) cached in registers ----
  short8_t w62c[8];
#pragma unroll
  for (int f = 0; f < 8; ++f) w62c[f] = ldW(sW + OFF_W62, f, l);

  // neighbor bpermute addresses (same quarter, row cc = (c&8) + 2*bp + (c&1))
  const int b_ln = (c >> 1) & 3;
  int vnb[3];
#pragma unroll
  for (int j = 0; j < 3; ++j) {
    const int bp = j + (j >= b_ln);
    vnb[j] = ((l & 48) + (c & 8) + 2 * bp + (c & 1)) << 2;
  }

  const int wslot = blockIdx.x * NWAVE + wave;

#pragma unroll 1
  for (int pi = 0; pi < PPW; ++pi) {
    const int g0 = (wslot * PPW + pi) * 2;   // 2 graphs: g0, g0+1
    if (g0 + 2 > p.gtot) break;

    // ---------------- pre-layer: a^T and e^T B-frags in registers ----------------
    short8_t af0, af1, ef0, ef1;
    {
      const float apv = p.ap[(g0 + (c >> 3)) * 4 + ((c >> 1) & 3)];
      const float e0v = p.ef[(g0 + (c >> 3)) * 16 + (c & 7) * 2];
      const float e1v = p.ef[(g0 + (c >> 3)) * 16 + (c & 7) * 2 + 1];
#pragma unroll
      for (int f = 0; f < 2; ++f) {
        const int base = 32 * f + 8 * qp;
        const float4 wa0 = *(const float4*)(sConst + CWPA + base);
        const float4 wa1 = *(const float4*)(sConst + CWPA + base + 4);
        const float4 ba0 = *(const float4*)(sConst + CBPA + base);
        const float4 ba1 = *(const float4*)(sConst + CBPA + base + 4);
        uint4 pa;
        pa.x = pk2(fmaxf(fmaf(apv, wa0.x, ba0.x), 0.f), fmaxf(fmaf(apv, wa0.y, ba0.y), 0.f));
        pa.y = pk2(fmaxf(fmaf(apv, wa0.z, ba0.z), 0.f), fmaxf(fmaf(apv, wa0.w, ba0.w), 0.f));
        pa.z = pk2(fmaxf(fmaf(apv, wa1.x, ba1.x), 0.f), fmaxf(fmaf(apv, wa1.y, ba1.y), 0.f));
        pa.w = pk2(fmaxf(fmaf(apv, wa1.z, ba1.z), 0.f), fmaxf(fmaf(apv, wa1.w, ba1.w), 0.f));
        const float4 w00 = *(const float4*)(sConst + CWPE + base);
        const float4 w01 = *(const float4*)(sConst + CWPE + base + 4);
        const float4 w10 = *(const float4*)(sConst + CWPE + 64 + base);
        const float4 w11 = *(const float4*)(sConst + CWPE + 64 + base + 4);
        const float4 be0 = *(const float4*)(sConst + CBPE + base);
        const float4 be1 = *(const float4*)(sConst + CBPE + base + 4);
        uint4 pe;
        pe.x = pk2(fmaxf(fmaf(e0v, w00.x, fmaf(e1v, w10.x, be0.x)), 0.f),
                   fmaxf(fmaf(e0v, w00.y, fmaf(e1v, w10.y, be0.y)), 0.f));
        pe.y = pk2(fmaxf(fmaf(e0v, w00.z, fmaf(e1v, w10.z, be0.z)), 0.f),
                   fmaxf(fmaf(e0v, w00.w, fmaf(e1v, w10.w, be0.w)), 0.f));
        pe.z = pk2(fmaxf(fmaf(e0v, w01.x, fmaf(e1v, w11.x, be1.x)), 0.f),
                   fmaxf(fmaf(e0v, w01.y, fmaf(e1v, w11.y, be1.y)), 0.f));
        pe.w = pk2(fmaxf(fmaf(e0v, w01.z, fmaf(e1v, w11.z, be1.z)), 0.f),
                   fmaxf(fmaf(e0v, w01.w, fmaf(e1v, w11.w, be1.w)), 0.f));
        if (f == 0) { af0 = __builtin_bit_cast(short8_t, pa); ef0 = __builtin_bit_cast(short8_t, pe); }
        else        { af1 = __builtin_bit_cast(short8_t, pa); ef1 = __builtin_bit_cast(short8_t, pe); }
      }
    }

    // ---- aP^T = w61[:64]^T a^T, b61 folded, packed raw (iteration-invariant) ----
    u32 aPf[8];
    {
      floatx4 acc[4];
      init0(acc);
      layerT<4>(acc, sW + OFF_W61, af0, af1, l);
#pragma unroll
      for (int t = 0; t < 4; ++t) {
        const float4 bv = *(const float4*)(sConst + CB61 + 16 * t + 4 * qp);
        aPf[2 * t + 0] = pk2(acc[t][0] + bv.x, acc[t][1] + bv.y);
        aPf[2 * t + 1] = pk2(acc[t][2] + bv.z, acc[t][3] + bv.w);
      }
    }

    // ---------------- 2 shared-weight update iterations ----------------
#pragma unroll 1
    for (int it = 0; it < 2; ++it) {
      // ---- mlp5 -> m1 (packed raw; relu deferred to agg pkmax) ----
      u32 m1p[8];
      {
        floatx4 acc[4];
        initB(acc, sConst + CB51, qp);
        layerT128(acc, sW + OFF_W51, af0, af1, ef0, ef1, l);
        short8_t t0, t1;
        packRf(t0, t1, acc);
        initB(acc, sConst + CB52, qp);
        layerT<2>(acc, sW + OFF_W52, t0, t1, l);
        packRf(t0, t1, acc);
        initB(acc, sConst + CB53, qp);
        layerT<2>(acc, sW + OFF_W53, t0, t1, l);
        pack0(m1p, acc);
      }

      // ---- eP^T = w61[64:]^T e^T (raw pack; b61 lives in aPf) ----
      u32 ePp[8];
      {
        floatx4 acc[4];
        init0(acc);
        layerT<4>(acc, sW + OFF_W61 + 2 * 512, ef0, ef1, l);
        pack0(ePp, acc);
      }

      // ---- mlp6 -> m2: 3 neighbor tiles, h via same-quarter bpermute ----
      u32 m2p[8];
#pragma unroll
      for (int j = 0; j < 3; ++j) {
        u32 hp[8];
#pragma unroll
        for (int i = 0; i < 8; ++i) {
          const u32 ep = (u32)__builtin_amdgcn_ds_bpermute(vnb[j], (int)ePp[i]);
          hp[i] = pk2(fmaxf(blo(aPf[i]) + blo(ep), 0.f),
                      fmaxf(bhi(aPf[i]) + bhi(ep), 0.f));
        }
        const short8_t h0 = mkf(hp[0], hp[2], hp[4], hp[6]);
        const short8_t h1 = mkf(hp[1], hp[3], hp[5], hp[7]);
        floatx4 acc[4];
        initB(acc, sConst + CB62, qp);
        layerB(acc, w62c, h0, h1);
        short8_t t0, t1;
        packRf(t0, t1, acc);
        initB(acc, sConst + CB63, qp);
        layerT<2>(acc, sW + OFF_W63, t0, t1, l);
        u32 cd[8];
        pack0(cd, acc);
#pragma unroll
        for (int i = 0; i < 8; ++i)
          m2p[i] = (j == 0) ? cd[i] : pkmax(m2p[i], cd[i]);
      }

      // ---- agg = relu(max(m1[lane^1], m2)) + mlp7 ----
      {
        u32 agp[8];
#pragma unroll
        for (int i = 0; i < 8; ++i)
          agp[i] = pkmax(pkmax(swz1(m1p[i]), m2p[i]), 0u);
        const short8_t g0f = mkf(agp[0], agp[2], agp[4], agp[6]);
        const short8_t g1f = mkf(agp[1], agp[3], agp[5], agp[7]);
        floatx4 acc[4];
        initB(acc, sConst + CB71, qp);
        layerT128(acc, sW + OFF_W71, g0f, g1f, ef0, ef1, l);
        short8_t t0, t1;
        packRf(t0, t1, acc);
        initB(acc, sConst + CB72, qp);
        layerT<2>(acc, sW + OFF_W72, t0, t1, l);
        packRf(t0, t1, acc);
        initB(acc, sConst + CB73, qp);
        layerT<2>(acc, sW + OFF_W73, t0, t1, l);

        if (it == 0) {
          packRf(ef0, ef1, acc);   // new e^T stays in registers
        } else {
          // ---- post linear + per-(g,b) L2 row normalization ----
          float prr = 0.f, pii = 0.f;
#pragma unroll
          for (int t = 0; t < 4; ++t) {
            const float4 wr = *(const float4*)(sConst + CWPO + 16 * t + 4 * qp);
            const float4 wi = *(const float4*)(sConst + CWPO + 64 + 16 * t + 4 * qp);
            const float e0 = fmaxf(acc[t][0], 0.f);
            const float e1 = fmaxf(acc[t][1], 0.f);
            const float e2 = fmaxf(acc[t][2], 0.f);
            const float e3 = fmaxf(acc[t][3], 0.f);
            prr = fmaf(e0, wr.x, prr); pii = fmaf(e0, wi.x, pii);
            prr = fmaf(e1, wr.y, prr); pii = fmaf(e1, wi.y, pii);
            prr = fmaf(e2, wr.z, prr); pii = fmaf(e2, wi.z, pii);
            prr = fmaf(e3, wr.w, prr); pii = fmaf(e3, wi.w, pii);
          }
          // sum over the 4 lane quarters (same c)
          prr += __shfl_xor(prr, 16, 64); prr += __shfl_xor(prr, 32, 64);
          pii += __shfl_xor(pii, 16, 64); pii += __shfl_xor(pii, 32, 64);
          prr += sConst[CBPO];
          pii += sConst[CBPO + 1];
          // k-neighbor (row c^1) magnitudes
          const float prn = __uint_as_float(swz1(__float_as_uint(prr)));
          const float pin = __uint_as_float(swz1(__float_as_uint(pii)));
          const float n2 = prr * prr + pii * pii + prn * prn + pin * pin;
          if (qp < 2)
            p.out[g0 * 16 + c * 2 + qp] = ((qp == 0) ? prr : pii) / sqrtf(n2);
        }
      }
    }
  }
}

extern "C" void kernel_launch(void* const* d_in, const int* in_sizes, int n_in,
                              void* d_out, int out_size, void* d_ws, size_t ws_size,
                              hipStream_t stream) {
  Params p;
  p.ap    = (const float*)d_in[0];
  p.ef    = (const float*)d_in[1];
  p.wpa   = (const float*)d_in[2];  p.bpa   = (const float*)d_in[3];
  p.wpe   = (const float*)d_in[4];  p.bpe   = (const float*)d_in[5];
  p.w51   = (const float*)d_in[6];  p.b51   = (const float*)d_in[7];
  p.w52   = (const float*)d_in[8];  p.b52   = (const float*)d_in[9];
  p.w53   = (const float*)d_in[10]; p.b53   = (const float*)d_in[11];
  p.w61   = (const float*)d_in[12]; p.b61   = (const float*)d_in[13];
  p.w62   = (const float*)d_in[14]; p.b62   = (const float*)d_in[15];
  p.w63   = (const float*)d_in[16]; p.b63   = (const float*)d_in[17];
  p.w71   = (const float*)d_in[18]; p.b71   = (const float*)d_in[19];
  p.w72   = (const float*)d_in[20]; p.b72   = (const float*)d_in[21];
  p.w73   = (const float*)d_in[22]; p.b73   = (const float*)d_in[23];
  p.wpost = (const float*)d_in[24]; p.bpost = (const float*)d_in[25];
  p.out   = (float*)d_out;
  p.gtot  = in_sizes[0] / 4;  // G from ap_feat [G,B,1]

  hipLaunchKernelGGL(hetgnn_mfma, dim3(NBLK), dim3(512), 0, stream, p);
}

// Round 6
// 406.474 us; speedup vs baseline: 1.0273x; 1.0273x over previous
//
#include <hip/hip_runtime.h>

// HetGNN fused kernel, round 20: transposed orientation, register-dieted to
// the empirical 128-VGPR cap.
// R19 proved the structure (SQ_LDS_BANK_CONFLICT 5.37M -> 0, activation LDS
// gone) but peak live demand ~160-180 regs blew the allocator's hard 128 cap
// (6 rounds of evidence: attributes never move it) -> inner-loop arrays
// spilled, 1.3 GB scratch traffic, 327 us. Fix: drop the w62c register cache
// (-32 regs; w62's sW layout is already TS=2, read it like w63). Peak live
// ~100 regs <= 128 -> no spill. Everything else identical to R19:
//  - every layer computed output-transposed (A-operand = weight, B = act),
//    fixed k-permutation pi baked into weight staging makes each lane's
//    packed accumulator pairs directly the next layer's B-frags;
//  - zero activation LDS, zero scatters; glue = 8 ds_bpermute per neighbor
//    tile + ds_swizzle lane^1 for the m1 k-swap + epilogue shuffles.
// Expected regime: LDS-weight-read bound (~160 ds_read_b128/it/wave).

typedef unsigned short u16;
typedef unsigned int   u32;
typedef __attribute__((ext_vector_type(8))) short short8_t;
typedef __attribute__((ext_vector_type(2))) short short2v;
typedef __attribute__((ext_vector_type(4))) float floatx4;

// u16 offsets of each matrix's fragment block inside sW (fi*512 ordering).
// 96 frags: w51(16) w61(16) w71(16) w52(8) w53(8) w62(8) w63(8) w72(8) w73(8).
#define OFF_W51 0
#define OFF_W61 8192
#define OFF_W71 16384
#define OFF_W52 24576
#define OFF_W53 28672
#define OFF_W62 32768
#define OFF_W63 36864
#define OFF_W72 40960
#define OFF_W73 45056
#define WS_U16  49152

// f32 offsets inside the sConst LDS table.
// CB*: biases in NATURAL f_out order (read as float4 at 16t+4p).
// CWPO: wpost de-interleaved: [0..63] real, [64..127] imag (natural order).
// CWPA/CBPA/CBPE: 64 floats in pi-slot order (32f + 8p + j).
// CWPE: 2 x 64 in pi-slot order.
#define CB51 0
#define CB52 64
#define CB53 128
#define CB61 192
#define CB62 256
#define CB63 320
#define CB71 384
#define CB72 448
#define CB73 512
#define CWPO 576
#define CBPO 704
#define CWPA 768
#define CBPA 832
#define CWPE 896
#define CBPE 1024
#define CSZ  1088

struct Params {
  const float *ap, *ef;
  const float *wpa, *bpa, *wpe, *bpe;
  const float *w51, *b51, *w52, *b52, *w53, *b53;
  const float *w61, *b61, *w62, *b62, *w63, *b63;
  const float *w71, *b71, *w72, *b72, *w73, *b73;
  const float *wpost, *bpost;
  float *out;
  int gtot;
};

// Pack two f32 to bf16 pair: round-half-up via +0x8000, then one byte-perm.
// Low half = first arg (= even slot j).
__device__ __forceinline__ u32 pk2(float a, float b) {
  const u32 ua = __float_as_uint(a) + 0x8000u;
  const u32 ub = __float_as_uint(b) + 0x8000u;
  return __builtin_amdgcn_perm(ub, ua, 0x07060302u);  // {ub[31:16], ua[31:16]}
}
__device__ __forceinline__ float blo(u32 v) { return __uint_as_float(v << 16); }
__device__ __forceinline__ float bhi(u32 v) { return __uint_as_float(v & 0xffff0000u); }
// packed int16 max: exact bf16-max in our use because the final max-with-0
// (deferred relu) dominates any mis-ordered negative intermediate.
__device__ __forceinline__ u32 pkmax(u32 a, u32 b) {
  const short2v r = __builtin_elementwise_max(__builtin_bit_cast(short2v, a),
                                              __builtin_bit_cast(short2v, b));
  return __builtin_bit_cast(u32, r);
}
// lane ^= 1 exchange (BitMode swizzle, xor=1): rows (g,b,k) <-> (g,b,k^1).
__device__ __forceinline__ u32 swz1(u32 x) {
  return (u32)__builtin_amdgcn_ds_swizzle((int)x, 0x041F);
}

__device__ __forceinline__ floatx4 mfma16(short8_t a, short8_t b, floatx4 c) {
  return __builtin_amdgcn_mfma_f32_16x16x32_bf16(a, b, c, 0, 0, 0);
}
__device__ __forceinline__ short8_t ldW(const u16* B, int f, int l) {
  return *(const short8_t*)(B + f * 512 + l * 8);
}
__device__ __forceinline__ short8_t mkf(u32 a, u32 b, u32 c, u32 d) {
  uint4 v; v.x = a; v.y = b; v.z = c; v.w = d;
  return __builtin_bit_cast(short8_t, v);
}

__device__ __forceinline__ void init0(floatx4* acc) {
#pragma unroll
  for (int t = 0; t < 4; ++t) { acc[t][0] = 0.f; acc[t][1] = 0.f; acc[t][2] = 0.f; acc[t][3] = 0.f; }
}
// Bias init: acc[t][r] = bias[16t + 4p + r] (f_out-indexed, broadcast b128).
__device__ __forceinline__ void initB(floatx4* acc, const float* cb, int qp) {
#pragma unroll
  for (int t = 0; t < 4; ++t) {
    const float4 b = *(const float4*)(cb + 16 * t + 4 * qp);
    acc[t][0] = b.x; acc[t][1] = b.y; acc[t][2] = b.z; acc[t][3] = b.w;
  }
}

// 64->64 layer, weights from LDS: frags (t*TS+0, t*TS+1).
template<int TS>
__device__ __forceinline__ void layerT(floatx4* acc, const u16* W,
                                       short8_t b0, short8_t b1, int l) {
#pragma unroll
  for (int t = 0; t < 4; ++t) {
    acc[t] = mfma16(ldW(W, t * TS + 0, l), b0, acc[t]);
    acc[t] = mfma16(ldW(W, t * TS + 1, l), b1, acc[t]);
  }
}
// K=128 layer (concat input = 4 B-frags), weights = 16 frags (t*4+h).
__device__ __forceinline__ void layerT128(floatx4* acc, const u16* W,
                                          short8_t f0, short8_t f1,
                                          short8_t f2, short8_t f3, int l) {
#pragma unroll
  for (int t = 0; t < 4; ++t) {
    acc[t] = mfma16(ldW(W, t * 4 + 0, l), f0, acc[t]);
    acc[t] = mfma16(ldW(W, t * 4 + 1, l), f1, acc[t]);
    acc[t] = mfma16(ldW(W, t * 4 + 2, l), f2, acc[t]);
    acc[t] = mfma16(ldW(W, t * 4 + 3, l), f3, acc[t]);
  }
}

// relu + pack acc -> next-layer B-frags (pi order: frag0 = pk01[t], frag1 = pk23[t]).
__device__ __forceinline__ void packRf(short8_t& f0, short8_t& f1, const floatx4* a) {
  uint4 u0, u1;
  u0.x = pk2(fmaxf(a[0][0], 0.f), fmaxf(a[0][1], 0.f));
  u1.x = pk2(fmaxf(a[0][2], 0.f), fmaxf(a[0][3], 0.f));
  u0.y = pk2(fmaxf(a[1][0], 0.f), fmaxf(a[1][1], 0.f));
  u1.y = pk2(fmaxf(a[1][2], 0.f), fmaxf(a[1][3], 0.f));
  u0.z = pk2(fmaxf(a[2][0], 0.f), fmaxf(a[2][1], 0.f));
  u1.z = pk2(fmaxf(a[2][2], 0.f), fmaxf(a[2][3], 0.f));
  u0.w = pk2(fmaxf(a[3][0], 0.f), fmaxf(a[3][1], 0.f));
  u1.w = pk2(fmaxf(a[3][2], 0.f), fmaxf(a[3][3], 0.f));
  f0 = __builtin_bit_cast(short8_t, u0);
  f1 = __builtin_bit_cast(short8_t, u1);
}
// raw pack (relu deferred): d[2t] = pk(r0,r1), d[2t+1] = pk(r2,r3).
__device__ __forceinline__ void pack0(u32* d, const floatx4* a) {
#pragma unroll
  for (int t = 0; t < 4; ++t) {
    d[2 * t + 0] = pk2(a[t][0], a[t][1]);
    d[2 * t + 1] = pk2(a[t][2], a[t][3]);
  }
}

#define NBLK 256
#define NWAVE 8
#define PPW  4   // 256 blk * 8 waves * 4 pairs = 8192 pairs = 16384 graphs

__global__ __launch_bounds__(512, 2)
__attribute__((amdgpu_waves_per_eu(2, 2)))
void hetgnn_mfma(Params p) {
  __shared__ __align__(16) u16   sW[WS_U16];   // 96 KB weights (pi-k-order A-frags)
  __shared__ __align__(16) float sConst[CSZ];  // 4.25 KB

  const int tid  = threadIdx.x;
  const int wave = tid >> 6;
  const int l    = tid & 63;
  const int qp   = l >> 4;   // lane quarter
  const int c    = l & 15;   // graph-row column: (g = c>>3, b = (c>>1)&3, k = c&1)

  // ---- stage + swizzle weights: f32 global -> bf16 A-frags in pi-k-order.
  //      A-frag (t,h): value(lane l, j) = W[kidx, 16t + (l&15)]
  //      K=64 mats:  kidx = 16*(j>>1) + 4*(l>>4) + 2*h + (j&1)
  //      K=128 mats: kidx = 64*(h>>1) + 16*(j>>1) + 4*(l>>4) + 2*(h&1) + (j&1)
  {
    for (int fi = wave; fi < 96; fi += NWAVE) {   // wave-uniform fi, 12/wave
      int t, h, mi;
      if (fi < 48) { mi = fi >> 4; const int loc = fi & 15; t = loc >> 2; h = loc & 3; }
      else { const int j2 = fi - 48; mi = 3 + (j2 >> 3); const int loc = j2 & 7; t = loc >> 1; h = loc & 1; }
      const float* W =
          (mi == 0) ? p.w51 : (mi == 1) ? p.w61 : (mi == 2) ? p.w71 :
          (mi == 3) ? p.w52 : (mi == 4) ? p.w53 : (mi == 5) ? p.w62 :
          (mi == 6) ? p.w63 : (mi == 7) ? p.w72 : p.w73;
      const int nn = 16 * t + c;
      float w[8];
#pragma unroll
      for (int jj = 0; jj < 8; ++jj) {
        const int kidx = (fi < 48)
            ? 64 * (h >> 1) + 16 * (jj >> 1) + 4 * qp + 2 * (h & 1) + (jj & 1)
            : 16 * (jj >> 1) + 4 * qp + 2 * h + (jj & 1);
        w[jj] = W[kidx * 64 + nn];
      }
      uint4 o;
      o.x = pk2(w[0], w[1]); o.y = pk2(w[2], w[3]);
      o.z = pk2(w[4], w[5]); o.w = pk2(w[6], w[7]);
      *(uint4*)(sW + fi * 512 + l * 8) = o;
    }
  }
  if (tid < 64) {
    // biases: natural f_out order
    sConst[CB51 + tid] = p.b51[tid];
    sConst[CB52 + tid] = p.b52[tid];
    sConst[CB53 + tid] = p.b53[tid];
    sConst[CB61 + tid] = p.b61[tid];
    sConst[CB62 + tid] = p.b62[tid];
    sConst[CB63 + tid] = p.b63[tid];
    sConst[CB71 + tid] = p.b71[tid];
    sConst[CB72 + tid] = p.b72[tid];
    sConst[CB73 + tid] = p.b73[tid];
    // wpost de-interleaved (natural order)
    sConst[CWPO + tid]      = p.wpost[2 * tid];
    sConst[CWPO + 64 + tid] = p.wpost[2 * tid + 1];
    // pre-layer weights/biases in pi-slot order: slot tid = 32f + 8p + j
    {
      const int f = tid >> 5, pp = (tid >> 3) & 3, jj = tid & 7;
      const int feat = 16 * (jj >> 1) + 4 * pp + 2 * f + (jj & 1);
      sConst[CWPA + tid] = p.wpa[feat];
      sConst[CBPA + tid] = p.bpa[feat];
      sConst[CBPE + tid] = p.bpe[feat];
    }
  }
  if (tid < 128) {
    const int s = tid & 63;
    const int f = s >> 5, pp = (s >> 3) & 3, jj = s & 7;
    const int feat = 16 * (jj >> 1) + 4 * pp + 2 * f + (jj & 1);
    sConst[CWPE + tid] = p.wpe[(tid >> 6) * 64 + feat];
  }
  if (tid < 2) sConst[CBPO + tid] = p.bpost[tid];
  __syncthreads();

  // neighbor bpermute addresses (same quarter, row cc = (c&8) + 2*bp + (c&1))
  const int b_ln = (c >> 1) & 3;
  int vnb[3];
#pragma unroll
  for (int j = 0; j < 3; ++j) {
    const int bp = j + (j >= b_ln);
    vnb[j] = ((l & 48) + (c & 8) + 2 * bp + (c & 1)) << 2;
  }

  const int wslot = blockIdx.x * NWAVE + wave;

#pragma unroll 1
  for (int pi = 0; pi < PPW; ++pi) {
    const int g0 = (wslot * PPW + pi) * 2;   // 2 graphs: g0, g0+1
    if (g0 + 2 > p.gtot) break;

    // ---------------- pre-layer: a^T and e^T B-frags in registers ----------------
    short8_t af0, af1, ef0, ef1;
    {
      const float apv = p.ap[(g0 + (c >> 3)) * 4 + ((c >> 1) & 3)];
      const float e0v = p.ef[(g0 + (c >> 3)) * 16 + (c & 7) * 2];
      const float e1v = p.ef[(g0 + (c >> 3)) * 16 + (c & 7) * 2 + 1];
#pragma unroll
      for (int f = 0; f < 2; ++f) {
        const int base = 32 * f + 8 * qp;
        const float4 wa0 = *(const float4*)(sConst + CWPA + base);
        const float4 wa1 = *(const float4*)(sConst + CWPA + base + 4);
        const float4 ba0 = *(const float4*)(sConst + CBPA + base);
        const float4 ba1 = *(const float4*)(sConst + CBPA + base + 4);
        uint4 pa;
        pa.x = pk2(fmaxf(fmaf(apv, wa0.x, ba0.x), 0.f), fmaxf(fmaf(apv, wa0.y, ba0.y), 0.f));
        pa.y = pk2(fmaxf(fmaf(apv, wa0.z, ba0.z), 0.f), fmaxf(fmaf(apv, wa0.w, ba0.w), 0.f));
        pa.z = pk2(fmaxf(fmaf(apv, wa1.x, ba1.x), 0.f), fmaxf(fmaf(apv, wa1.y, ba1.y), 0.f));
        pa.w = pk2(fmaxf(fmaf(apv, wa1.z, ba1.z), 0.f), fmaxf(fmaf(apv, wa1.w, ba1.w), 0.f));
        const float4 w00 = *(const float4*)(sConst + CWPE + base);
        const float4 w01 = *(const float4*)(sConst + CWPE + base + 4);
        const float4 w10 = *(const float4*)(sConst + CWPE + 64 + base);
        const float4 w11 = *(const float4*)(sConst + CWPE + 64 + base + 4);
        const float4 be0 = *(const float4*)(sConst + CBPE + base);
        const float4 be1 = *(const float4*)(sConst + CBPE + base + 4);
        uint4 pe;
        pe.x = pk2(fmaxf(fmaf(e0v, w00.x, fmaf(e1v, w10.x, be0.x)), 0.f),
                   fmaxf(fmaf(e0v, w00.y, fmaf(e1v, w10.y, be0.y)), 0.f));
        pe.y = pk2(fmaxf(fmaf(e0v, w00.z, fmaf(e1v, w10.z, be0.z)), 0.f),
                   fmaxf(fmaf(e0v, w00.w, fmaf(e1v, w10.w, be0.w)), 0.f));
        pe.z = pk2(fmaxf(fmaf(e0v, w01.x, fmaf(e1v, w11.x, be1.x)), 0.f),
                   fmaxf(fmaf(e0v, w01.y, fmaf(e1v, w11.y, be1.y)), 0.f));
        pe.w = pk2(fmaxf(fmaf(e0v, w01.z, fmaf(e1v, w11.z, be1.z)), 0.f),
                   fmaxf(fmaf(e0v, w01.w, fmaf(e1v, w11.w, be1.w)), 0.f));
        if (f == 0) { af0 = __builtin_bit_cast(short8_t, pa); ef0 = __builtin_bit_cast(short8_t, pe); }
        else        { af1 = __builtin_bit_cast(short8_t, pa); ef1 = __builtin_bit_cast(short8_t, pe); }
      }
    }

    // ---- aP^T = w61[:64]^T a^T, b61 folded, packed raw (iteration-invariant) ----
    u32 aPf[8];
    {
      floatx4 acc[4];
      init0(acc);
      layerT<4>(acc, sW + OFF_W61, af0, af1, l);
#pragma unroll
      for (int t = 0; t < 4; ++t) {
        const float4 bv = *(const float4*)(sConst + CB61 + 16 * t + 4 * qp);
        aPf[2 * t + 0] = pk2(acc[t][0] + bv.x, acc[t][1] + bv.y);
        aPf[2 * t + 1] = pk2(acc[t][2] + bv.z, acc[t][3] + bv.w);
      }
    }

    // ---------------- 2 shared-weight update iterations ----------------
#pragma unroll 1
    for (int it = 0; it < 2; ++it) {
      // ---- mlp5 -> m1 (packed raw; relu deferred to agg pkmax) ----
      u32 m1p[8];
      {
        floatx4 acc[4];
        initB(acc, sConst + CB51, qp);
        layerT128(acc, sW + OFF_W51, af0, af1, ef0, ef1, l);
        short8_t t0, t1;
        packRf(t0, t1, acc);
        initB(acc, sConst + CB52, qp);
        layerT<2>(acc, sW + OFF_W52, t0, t1, l);
        packRf(t0, t1, acc);
        initB(acc, sConst + CB53, qp);
        layerT<2>(acc, sW + OFF_W53, t0, t1, l);
        pack0(m1p, acc);
      }

      // ---- eP^T = w61[64:]^T e^T (raw pack; b61 lives in aPf) ----
      u32 ePp[8];
      {
        floatx4 acc[4];
        init0(acc);
        layerT<4>(acc, sW + OFF_W61 + 2 * 512, ef0, ef1, l);
        pack0(ePp, acc);
      }

      // ---- mlp6 -> m2: 3 neighbor tiles, h via same-quarter bpermute ----
      u32 m2p[8];
#pragma unroll
      for (int j = 0; j < 3; ++j) {
        u32 hp[8];
#pragma unroll
        for (int i = 0; i < 8; ++i) {
          const u32 ep = (u32)__builtin_amdgcn_ds_bpermute(vnb[j], (int)ePp[i]);
          hp[i] = pk2(fmaxf(blo(aPf[i]) + blo(ep), 0.f),
                      fmaxf(bhi(aPf[i]) + bhi(ep), 0.f));
        }
        const short8_t h0 = mkf(hp[0], hp[2], hp[4], hp[6]);
        const short8_t h1 = mkf(hp[1], hp[3], hp[5], hp[7]);
        floatx4 acc[4];
        initB(acc, sConst + CB62, qp);
        layerT<2>(acc, sW + OFF_W62, h0, h1, l);
        short8_t t0, t1;
        packRf(t0, t1, acc);
        initB(acc, sConst + CB63, qp);
        layerT<2>(acc, sW + OFF_W63, t0, t1, l);
        u32 cd[8];
        pack0(cd, acc);
#pragma unroll
        for (int i = 0; i < 8; ++i)
          m2p[i] = (j == 0) ? cd[i] : pkmax(m2p[i], cd[i]);
      }

      // ---- agg = relu(max(m1[lane^1], m2)) + mlp7 ----
      {
        u32 agp[8];
#pragma unroll
        for (int i = 0; i < 8; ++i)
          agp[i] = pkmax(pkmax(swz1(m1p[i]), m2p[i]), 0u);
        const short8_t g0f = mkf(agp[0], agp[2], agp[4], agp[6]);
        const short8_t g1f = mkf(agp[1], agp[3], agp[5], agp[7]);
        floatx4 acc[4];
        initB(acc, sConst + CB71, qp);
        layerT128(acc, sW + OFF_W71, g0f, g1f, ef0, ef1, l);
        short8_t t0, t1;
        packRf(t0, t1, acc);
        initB(acc, sConst + CB72, qp);
        layerT<2>(acc, sW + OFF_W72, t0, t1, l);
        packRf(t0, t1, acc);
        initB(acc, sConst + CB73, qp);
        layerT<2>(acc, sW + OFF_W73, t0, t1, l);

        if (it == 0) {
          packRf(ef0, ef1, acc);   // new e^T stays in registers
        } else {
          // ---- post linear + per-(g,b) L2 row normalization ----
          float prr = 0.f, pii = 0.f;
#pragma unroll
          for (int t = 0; t < 4; ++t) {
            const float4 wr = *(const float4*)(sConst + CWPO + 16 * t + 4 * qp);
            const float4 wi = *(const float4*)(sConst + CWPO + 64 + 16 * t + 4 * qp);
            const float e0 = fmaxf(acc[t][0], 0.f);
            const float e1 = fmaxf(acc[t][1], 0.f);
            const float e2 = fmaxf(acc[t][2], 0.f);
            const float e3 = fmaxf(acc[t][3], 0.f);
            prr = fmaf(e0, wr.x, prr); pii = fmaf(e0, wi.x, pii);
            prr = fmaf(e1, wr.y, prr); pii = fmaf(e1, wi.y, pii);
            prr = fmaf(e2, wr.z, prr); pii = fmaf(e2, wi.z, pii);
            prr = fmaf(e3, wr.w, prr); pii = fmaf(e3, wi.w, pii);
          }
          // sum over the 4 lane quarters (same c)
          prr += __shfl_xor(prr, 16, 64); prr += __shfl_xor(prr, 32, 64);
          pii += __shfl_xor(pii, 16, 64); pii += __shfl_xor(pii, 32, 64);
          prr += sConst[CBPO];
          pii += sConst[CBPO + 1];
          // k-neighbor (row c^1) magnitudes
          const float prn = __uint_as_float(swz1(__float_as_uint(prr)));
          const float pin = __uint_as_float(swz1(__float_as_uint(pii)));
          const float n2 = prr * prr + pii * pii + prn * prn + pin * pin;
          if (qp < 2)
            p.out[g0 * 16 + c * 2 + qp] = ((qp == 0) ? prr : pii) / sqrtf(n2);
        }
      }
    }
  }
}

extern "C" void kernel_launch(void* const* d_in, const int* in_sizes, int n_in,
                              void* d_out, int out_size, void* d_ws, size_t ws_size,
                              hipStream_t stream) {
  Params p;
  p.ap    = (const float*)d_in[0];
  p.ef    = (const float*)d_in[1];
  p.wpa   = (const float*)d_in[2];  p.bpa   = (const float*)d_in[3];
  p.wpe   = (const float*)d_in[4];  p.bpe   = (const float*)d_in[5];
  p.w51   = (const float*)d_in[6];  p.b51   = (const float*)d_in[7];
  p.w52   = (const float*)d_in[8];  p.b52   = (const float*)d_in[9];
  p.w53   = (const float*)d_in[10]; p.b53   = (const float*)d_in[11];
  p.w61   = (const float*)d_in[12]; p.b61   = (const float*)d_in[13];
  p.w62   = (const float*)d_in[14]; p.b62   = (const float*)d_in[15];
  p.w63   = (const float*)d_in[16]; p.b63   = (const float*)d_in[17];
  p.w71   = (const float*)d_in[18]; p.b71   = (const float*)d_in[19];
  p.w72   = (const float*)d_in[20]; p.b72   = (const float*)d_in[21];
  p.w73   = (const float*)d_in[22]; p.b73   = (const float*)d_in[23];
  p.wpost = (const float*)d_in[24]; p.bpost = (const float*)d_in[25];
  p.out   = (float*)d_out;
  p.gtot  = in_sizes[0] / 4;  // G from ap_feat [G,B,1]

  hipLaunchKernelGGL(hetgnn_mfma, dim3(NBLK), dim3(512), 0, stream, p);
}